// Round 1
// baseline (1634.817 us; speedup 1.0000x reference)
//
#include <hip/hip_runtime.h>
#include <math.h>

// ---------------------------------------------------------------------------
// MegaCartTensorOut: fused equivariant TP block.
//
// CG table layout in d_ws (floats):
//   instr i : offset OFF[i], size (2la+1)(2lb+1)(2lo+1)
//   i0 (0,0,0) off 0   sz 1
//   i1 (1,1,0) off 1   sz 9
//   i2 (2,2,0) off 10  sz 25
//   i3 (1,1,1) off 35  sz 27
//   i4 (2,2,1) off 62  sz 75
//   i5 (0,2,2) off 137 sz 25
//   i6 (2,0,2) off 162 sz 25
//   i7 (1,1,2) off 187 sz 45
//   i8 (2,2,2) off 232 sz 125   (end 357)
//   QB0 off 357 sz 9, QB1 off 366 sz 27, QB2 off 393 sz 45  -> total 438
// ---------------------------------------------------------------------------

#define N_CG_FLOATS 438

__device__ __forceinline__ double dfact(int n) {
  double r = 1.0;
  for (int i = 2; i <= n; ++i) r *= (double)i;
  return r;
}

__device__ void makeU(int l, double Ur[5][5], double Ui[5][5]) {
  for (int i = 0; i < 5; ++i)
    for (int j = 0; j < 5; ++j) { Ur[i][j] = 0.0; Ui[i][j] = 0.0; }
  Ur[l][l] = 1.0;
  const double is2 = 0.70710678118654752440;
  for (int m = 1; m <= l; ++m) {
    double sgn = (m & 1) ? -1.0 : 1.0;
    Ur[l + m][l + m] = sgn * is2;   // (-1)^m / sqrt2
    Ur[l + m][l - m] = is2;         // 1/sqrt2
    Ui[l - m][l + m] = -sgn * is2;  // -1j*(-1)^m/sqrt2
    Ui[l - m][l - m] = is2;         // 1j/sqrt2
  }
}

// Exact port of the reference's _real_cg (double precision), scaled by `scale`.
__device__ void compute_rcg(int l1, int l2, int l3, float* out, double scale) {
  const int n1 = 2 * l1 + 1, n2 = 2 * l2 + 1, n3 = 2 * l3 + 1;
  double C[5][5][5];
  for (int a = 0; a < 5; ++a)
    for (int b = 0; b < 5; ++b)
      for (int c = 0; c < 5; ++c) C[a][b][c] = 0.0;

  for (int m1 = -l1; m1 <= l1; ++m1)
    for (int m2 = -l2; m2 <= l2; ++m2) {
      int m3 = m1 + m2;
      if (m3 < -l3 || m3 > l3) continue;
      double pre = sqrt((2.0 * l3 + 1.0) * dfact(l1 + l2 - l3) * dfact(l1 - l2 + l3) *
                        dfact(-l1 + l2 + l3) / dfact(l1 + l2 + l3 + 1));
      pre *= sqrt(dfact(l3 + m3) * dfact(l3 - m3) * dfact(l1 - m1) * dfact(l1 + m1) *
                  dfact(l2 - m2) * dfact(l2 + m2));
      double s = 0.0;
      for (int k = 0; k <= l1 + l2 - l3; ++k) {
        int d1 = l1 + l2 - l3 - k, d2 = l1 - m1 - k, d3 = l2 + m2 - k;
        int d4 = l3 - l2 + m1 + k, d5 = l3 - l1 - m2 + k;
        if (d1 < 0 || d2 < 0 || d3 < 0 || d4 < 0 || d5 < 0) continue;
        double prod = dfact(k) * dfact(d1) * dfact(d2) * dfact(d3) * dfact(d4) * dfact(d5);
        s += ((k & 1) ? -1.0 : 1.0) / prod;
      }
      C[m1 + l1][m2 + l2][m3 + l3] = pre * s;
    }

  double U1r[5][5], U1i[5][5], U2r[5][5], U2i[5][5], U3r[5][5], U3i[5][5];
  makeU(l1, U1r, U1i);
  makeU(l2, U2r, U2i);
  makeU(l3, U3r, U3i);

  double Rre[5][5][5], Rim[5][5][5];
  double maxRe = 0.0, maxIm = 0.0;
  for (int a = 0; a < n1; ++a)
    for (int b = 0; b < n2; ++b)
      for (int c = 0; c < n3; ++c) {
        double sr = 0.0, si = 0.0;
        for (int m = 0; m < n1; ++m)
          for (int nn = 0; nn < n2; ++nn) {
            double t12r = U1r[a][m] * U2r[b][nn] - U1i[a][m] * U2i[b][nn];
            double t12i = U1r[a][m] * U2i[b][nn] + U1i[a][m] * U2r[b][nn];
            if (t12r == 0.0 && t12i == 0.0) continue;
            for (int o = 0; o < n3; ++o) {
              double cgv = C[m][nn][o];
              if (cgv == 0.0) continue;
              // * conj(U3[c][o])
              sr += (t12r * U3r[c][o] + t12i * U3i[c][o]) * cgv;
              si += (t12i * U3r[c][o] - t12r * U3i[c][o]) * cgv;
            }
          }
        Rre[a][b][c] = sr;
        Rim[a][b][c] = si;
        maxRe = fmax(maxRe, fabs(sr));
        maxIm = fmax(maxIm, fabs(si));
      }

  bool useRe = (maxRe >= maxIm);
  double nrm = 0.0;
  for (int a = 0; a < n1; ++a)
    for (int b = 0; b < n2; ++b)
      for (int c = 0; c < n3; ++c) {
        double vv = useRe ? Rre[a][b][c] : Rim[a][b][c];
        nrm += vv * vv;
      }
  nrm = sqrt(nrm);
  for (int a = 0; a < n1; ++a)
    for (int b = 0; b < n2; ++b)
      for (int c = 0; c < n3; ++c) {
        double vv = useRe ? Rre[a][b][c] : Rim[a][b][c];
        out[(a * n2 + b) * n3 + c] = (float)(vv / nrm * scale);
      }
}

__global__ void setup_cg(float* __restrict__ ws) {
  int t = threadIdx.x;
  const int LAs[9] = {0, 1, 2, 1, 2, 0, 2, 1, 2};
  const int LBs[9] = {0, 1, 2, 1, 2, 2, 0, 1, 2};
  const int LOs[9] = {0, 0, 0, 1, 1, 2, 2, 2, 2};
  const int OFF[9] = {0, 1, 10, 35, 62, 137, 162, 187, 232};
  if (t < 9) {
    compute_rcg(LAs[t], LBs[t], LOs[t], ws + OFF[t], 1.0);
  } else if (t < 12) {
    int l = t - 9;
    const int QOFF[3] = {357, 366, 393};
    compute_rcg(1, 1, l, ws + QOFF[l], sqrt(2.0 * l + 1.0));  // QB[l]
  }
}

// ---------------------------------------------------------------------------

template <int LA, int LB, int LO>
__device__ __forceinline__ void tp_accum(const float* __restrict__ R, float w,
                                         const float* xa, const float* xb, float* sph) {
  constexpr int NA = 2 * LA + 1, NB = 2 * LB + 1, NC = 2 * LO + 1;
#pragma unroll
  for (int a = 0; a < NA; ++a) {
#pragma unroll
    for (int b = 0; b < NB; ++b) {
      float xab = xa[a] * xb[b] * w;
#pragma unroll
      for (int c = 0; c < NC; ++c) sph[c] = fmaf(xab, R[(a * NB + b) * NC + c], sph[c]);
    }
  }
}

__global__ __launch_bounds__(256) void mega_node_kernel(
    const float* __restrict__ x_scalar, const float* __restrict__ x_sph,
    const int* __restrict__ batch, const float* __restrict__ W0, const float* __restrict__ W1,
    const float* __restrict__ W2, const float* __restrict__ A1, const float* __restrict__ b1,
    const float* __restrict__ A2, const float* __restrict__ b2, const float* __restrict__ p0,
    const float* __restrict__ p1, const float* __restrict__ p2, const float* __restrict__ cg_g,
    float* __restrict__ out, int N) {
  __shared__ float h_lds[8][64];
  __shared__ float cg[N_CG_FLOATS];

  const int t = threadIdx.x;
  for (int i = t; i < N_CG_FLOATS; i += 256) cg[i] = cg_g[i];

  const int nl = t >> 5;   // node within block (0..7)
  const int v = t & 31;    // TP channel
  int n = blockIdx.x * 8 + nl;
  const bool active = (n < N);
  if (!active) n = N - 1;

  // ---- h = silu(x_scalar @ A1 + b1); this lane computes cols v and v+32
  const float* xr = x_scalar + (long)n * 128;
  float a0 = b1[v], a1 = b1[v + 32];
  for (int j = 0; j < 128; ++j) {
    float xv = xr[j];
    a0 = fmaf(xv, A1[j * 64 + v], a0);
    a1 = fmaf(xv, A1[j * 64 + v + 32], a1);
  }
  h_lds[nl][v] = a0 / (1.0f + expf(-a0));
  h_lds[nl][v + 32] = a1 / (1.0f + expf(-a1));
  __syncthreads();

  // ---- channel mixes (out channel = v) + per-l RMS norm
  const float* sr = x_sph + (long)n * 480;
  float y0 = 0.f;
  for (int u = 0; u < 128; ++u) y0 = fmaf(sr[u], W0[u * 32 + v], y0);
  y0 *= 0.08838834764831845f;  // 1/sqrt(128)

  float y1[3] = {0.f, 0.f, 0.f};
  for (int u = 0; u < 64; ++u) {
    float wv = W1[u * 32 + v];
    const float* xp = sr + 128 + u * 3;
    y1[0] = fmaf(xp[0], wv, y1[0]);
    y1[1] = fmaf(xp[1], wv, y1[1]);
    y1[2] = fmaf(xp[2], wv, y1[2]);
  }
  y1[0] *= 0.125f; y1[1] *= 0.125f; y1[2] *= 0.125f;  // 1/sqrt(64)

  float y2[5] = {0.f, 0.f, 0.f, 0.f, 0.f};
  for (int u = 0; u < 32; ++u) {
    float wv = W2[u * 32 + v];
    const float* xp = sr + 320 + u * 5;
#pragma unroll
    for (int m = 0; m < 5; ++m) y2[m] = fmaf(xp[m], wv, y2[m]);
  }
#pragma unroll
  for (int m = 0; m < 5; ++m) y2[m] *= 0.17677669529663687f;  // 1/sqrt(32)

  float s0 = y0 * y0;
  float s1 = y1[0] * y1[0] + y1[1] * y1[1] + y1[2] * y1[2];
  float s2 = 0.f;
#pragma unroll
  for (int m = 0; m < 5; ++m) s2 = fmaf(y2[m], y2[m], s2);
#pragma unroll
  for (int msk = 16; msk >= 1; msk >>= 1) {
    s0 += __shfl_xor(s0, msk);
    s1 += __shfl_xor(s1, msk);
    s2 += __shfl_xor(s2, msk);
  }
  const float inv0 = 1.0f / sqrtf(s0 * (1.0f / 32.0f) + 1e-5f);
  const float inv1 = 1.0f / sqrtf(s1 * (1.0f / 96.0f) + 1e-5f);
  const float inv2 = 1.0f / sqrtf(s2 * (1.0f / 160.0f) + 1e-5f);
  float xs0[1] = {y0 * inv0};
  float xs1[3] = {y1[0] * inv1, y1[1] * inv1, y1[2] * inv1};
  float xs2[5];
#pragma unroll
  for (int m = 0; m < 5; ++m) xs2[m] = y2[m] * inv2;

  // ---- 9 TP instructions; coef folds alpha * p_path / sqrt(P)
  float sph0[1] = {0.f};
  float sph1[3] = {0.f, 0.f, 0.f};
  float sph2[5] = {0.f, 0.f, 0.f, 0.f, 0.f};
  const float invs32 = 0.17677669529663687f;                    // 1/sqrt(32)
  const float k0 = invs32 / 3.0f;                               // sqrt(1)/(3*sqrt32)
  const float k1 = 1.7320508075688772f * invs32 / 2.0f;         // sqrt(3)/(2*sqrt32)
  const float k2 = 2.23606797749979f * invs32 / 4.0f;           // sqrt(5)/(4*sqrt32)
  const float q00 = p0[0], q01 = p0[1], q02 = p0[2];
  const float q10 = p1[0], q11 = p1[1];
  const float q20 = p2[0], q21 = p2[1], q22 = p2[2], q23 = p2[3];

  float wv_;
#define CALC_W(IDX)                                                  \
  do {                                                               \
    wv_ = b2[(IDX)*32 + v];                                          \
    for (int k = 0; k < 64; ++k)                                     \
      wv_ = fmaf(h_lds[nl][k], A2[k * 288 + (IDX)*32 + v], wv_);     \
  } while (0)

  CALC_W(0); tp_accum<0, 0, 0>(cg + 0,   wv_ * (k0 * q00), xs0, xs0, sph0);
  CALC_W(1); tp_accum<1, 1, 0>(cg + 1,   wv_ * (k0 * q01), xs1, xs1, sph0);
  CALC_W(2); tp_accum<2, 2, 0>(cg + 10,  wv_ * (k0 * q02), xs2, xs2, sph0);
  CALC_W(3); tp_accum<1, 1, 1>(cg + 35,  wv_ * (k1 * q10), xs1, xs1, sph1);
  CALC_W(4); tp_accum<2, 2, 1>(cg + 62,  wv_ * (k1 * q11), xs2, xs2, sph1);
  CALC_W(5); tp_accum<0, 2, 2>(cg + 137, wv_ * (k2 * q20), xs0, xs2, sph2);
  CALC_W(6); tp_accum<2, 0, 2>(cg + 162, wv_ * (k2 * q21), xs2, xs0, sph2);
  CALC_W(7); tp_accum<1, 1, 2>(cg + 187, wv_ * (k2 * q22), xs1, xs1, sph2);
  CALC_W(8); tp_accum<2, 2, 2>(cg + 232, wv_ * (k2 * q23), xs2, xs2, sph2);
#undef CALC_W

  // ---- reduce sph over the 32 channel lanes
#pragma unroll
  for (int msk = 16; msk >= 1; msk >>= 1) {
    sph0[0] += __shfl_xor(sph0[0], msk);
#pragma unroll
    for (int m = 0; m < 3; ++m) sph1[m] += __shfl_xor(sph1[m], msk);
#pragma unroll
    for (int m = 0; m < 5; ++m) sph2[m] += __shfl_xor(sph2[m], msk);
  }

  // ---- cartesian transform + rolled segment-sum
  if (v == 0 && active) {
    const float* qb0 = cg + 357;
    const float* qb1 = cg + 366;
    const float* qb2 = cg + 393;
    float* og = out + (long)batch[n] * 9;
#pragma unroll
    for (int i = 0; i < 3; ++i) {
#pragma unroll
      for (int j = 0; j < 3; ++j) {
        float val = sph0[0] * qb0[i * 3 + j];
#pragma unroll
        for (int m = 0; m < 3; ++m) val = fmaf(sph1[m], qb1[(i * 3 + j) * 3 + m], val);
#pragma unroll
        for (int m = 0; m < 5; ++m) val = fmaf(sph2[m], qb2[(i * 3 + j) * 5 + m], val);
        // out[b, (i+1)%3, (j+1)%3] = g[b, i, j]
        atomicAdd(&og[((i + 1) % 3) * 3 + ((j + 1) % 3)], val);
      }
    }
  }
}

// ---------------------------------------------------------------------------

extern "C" void kernel_launch(void* const* d_in, const int* in_sizes, int n_in,
                              void* d_out, int out_size, void* d_ws, size_t ws_size,
                              hipStream_t stream) {
  const float* x_scalar = (const float*)d_in[0];
  const float* x_sph    = (const float*)d_in[1];
  const int*   batch    = (const int*)d_in[2];
  const float* W0 = (const float*)d_in[4];
  const float* W1 = (const float*)d_in[5];
  const float* W2 = (const float*)d_in[6];
  const float* A1 = (const float*)d_in[7];
  const float* b1 = (const float*)d_in[8];
  const float* A2 = (const float*)d_in[9];
  const float* b2 = (const float*)d_in[10];
  const float* p0 = (const float*)d_in[11];
  const float* p1 = (const float*)d_in[12];
  const float* p2 = (const float*)d_in[13];
  float* out = (float*)d_out;
  float* ws  = (float*)d_ws;

  const int N = in_sizes[0] / 128;

  hipMemsetAsync(d_out, 0, (size_t)out_size * sizeof(float), stream);
  setup_cg<<<1, 16, 0, stream>>>(ws);
  const int blocks = (N + 7) / 8;
  mega_node_kernel<<<blocks, 256, 0, stream>>>(x_scalar, x_sph, batch, W0, W1, W2, A1, b1, A2,
                                               b2, p0, p1, p2, ws, out, N);
}

// Round 2
// 322.527 us; speedup vs baseline: 5.0688x; 5.0688x over previous
//
#include <hip/hip_runtime.h>
#include <math.h>

// ---------------------------------------------------------------------------
// MegaCartTensorOut: fused equivariant TP block.
//
// CG table layout in d_ws (floats):
//   i0 (0,0,0) off 0   sz 1
//   i1 (1,1,0) off 1   sz 9
//   i2 (2,2,0) off 10  sz 25
//   i3 (1,1,1) off 35  sz 27
//   i4 (2,2,1) off 62  sz 75
//   i5 (0,2,2) off 137 sz 25
//   i6 (2,0,2) off 162 sz 25
//   i7 (1,1,2) off 187 sz 45
//   i8 (2,2,2) off 232 sz 125   (end 357)
//   QB0 off 357 sz 9, QB1 off 366 sz 27, QB2 off 393 sz 45  -> total 438
// ---------------------------------------------------------------------------

#define N_CG_FLOATS 438

__device__ __forceinline__ double dfact(int n) {
  double r = 1.0;
  for (int i = 2; i <= n; ++i) r *= (double)i;
  return r;
}

// U[l] element (row i = real m, col j = complex m): re + i*im
__device__ __forceinline__ void u_elem(int l, int i, int j, double& re, double& im) {
  re = 0.0; im = 0.0;
  const int mr = i - l, mc = j - l;
  const double is2 = 0.70710678118654752440;
  if (mr == 0) {
    if (mc == 0) re = 1.0;
  } else if (mr > 0) {
    if (mc == mr) re = ((mr & 1) ? -1.0 : 1.0) * is2;       // (-1)^m/sqrt2
    else if (mc == -mr) re = is2;                            // 1/sqrt2
  } else {  // mr < 0
    int m = -mr;
    if (mc == m) im = -(((m & 1) ? -1.0 : 1.0)) * is2;       // -1j*(-1)^m/sqrt2
    else if (mc == -m) im = is2;                             // 1j/sqrt2
  }
}

// One block per tensor; parallel over elements. Exact math of the reference.
__global__ void setup_cg_par(float* __restrict__ ws) {
  const int LAs[12] = {0, 1, 2, 1, 2, 0, 2, 1, 2, 1, 1, 1};
  const int LBs[12] = {0, 1, 2, 1, 2, 2, 0, 1, 2, 1, 1, 1};
  const int LOs[12] = {0, 0, 0, 1, 1, 2, 2, 2, 2, 0, 1, 2};
  const int OFF[12] = {0, 1, 10, 35, 62, 137, 162, 187, 232, 357, 366, 393};

  const int blk = blockIdx.x;
  const int l1 = LAs[blk], l2 = LBs[blk], l3 = LOs[blk];
  const double scale = (blk >= 9) ? sqrt(2.0 * l3 + 1.0) : 1.0;
  const int n1 = 2 * l1 + 1, n2 = 2 * l2 + 1, n3 = 2 * l3 + 1;
  const int nel = n1 * n2 * n3;
  const int t = threadIdx.x;

  __shared__ double Cs[125];
  __shared__ double Rre[125], Rim[125];
  __shared__ double s_inv;
  __shared__ int s_useRe;

  // phase 1: complex CG element (m1,m2,m3)
  if (t < nel) {
    const int i3 = t % n3, i2 = (t / n3) % n2, i1 = t / (n3 * n2);
    const int m1 = i1 - l1, m2 = i2 - l2, m3 = i3 - l3;
    double val = 0.0;
    if (m1 + m2 == m3) {
      double pre = sqrt((2.0 * l3 + 1.0) * dfact(l1 + l2 - l3) * dfact(l1 - l2 + l3) *
                        dfact(-l1 + l2 + l3) / dfact(l1 + l2 + l3 + 1));
      pre *= sqrt(dfact(l3 + m3) * dfact(l3 - m3) * dfact(l1 - m1) * dfact(l1 + m1) *
                  dfact(l2 - m2) * dfact(l2 + m2));
      double s = 0.0;
      for (int k = 0; k <= l1 + l2 - l3; ++k) {
        int d1 = l1 + l2 - l3 - k, d2 = l1 - m1 - k, d3 = l2 + m2 - k;
        int d4 = l3 - l2 + m1 + k, d5 = l3 - l1 - m2 + k;
        if (d1 < 0 || d2 < 0 || d3 < 0 || d4 < 0 || d5 < 0) continue;
        double prod = dfact(k) * dfact(d1) * dfact(d2) * dfact(d3) * dfact(d4) * dfact(d5);
        s += ((k & 1) ? -1.0 : 1.0) / prod;
      }
      val = pre * s;
    }
    Cs[t] = val;
  }
  __syncthreads();

  // phase 2: real CG element (a,b,c) = U1 x U2 x conj(U3) . C
  if (t < nel) {
    const int c = t % n3, bb = (t / n3) % n2, a = t / (n3 * n2);
    double sr_ = 0.0, si_ = 0.0;
    for (int m = 0; m < n1; ++m) {
      double u1r, u1i;
      u_elem(l1, a, m, u1r, u1i);
      if (u1r == 0.0 && u1i == 0.0) continue;
      for (int nn = 0; nn < n2; ++nn) {
        double u2r, u2i;
        u_elem(l2, bb, nn, u2r, u2i);
        double t12r = u1r * u2r - u1i * u2i;
        double t12i = u1r * u2i + u1i * u2r;
        if (t12r == 0.0 && t12i == 0.0) continue;
        for (int o = 0; o < n3; ++o) {
          double cgv = Cs[(m * n2 + nn) * n3 + o];
          if (cgv == 0.0) continue;
          double u3r, u3i;
          u_elem(l3, c, o, u3r, u3i);
          sr_ += (t12r * u3r + t12i * u3i) * cgv;  // * conj(U3)
          si_ += (t12i * u3r - t12r * u3i) * cgv;
        }
      }
    }
    Rre[t] = sr_;
    Rim[t] = si_;
  }
  __syncthreads();

  // phase 3: pick re/im by max-abs, Frobenius-normalize
  if (t == 0) {
    double maxRe = 0.0, maxIm = 0.0;
    for (int e = 0; e < nel; ++e) {
      maxRe = fmax(maxRe, fabs(Rre[e]));
      maxIm = fmax(maxIm, fabs(Rim[e]));
    }
    int useRe = (maxRe >= maxIm) ? 1 : 0;
    double nrm = 0.0;
    for (int e = 0; e < nel; ++e) {
      double v = useRe ? Rre[e] : Rim[e];
      nrm += v * v;
    }
    s_useRe = useRe;
    s_inv = scale / sqrt(nrm);
  }
  __syncthreads();

  if (t < nel) {
    double v = s_useRe ? Rre[t] : Rim[t];
    ws[OFF[blk] + t] = (float)(v * s_inv);
  }
}

// ---------------------------------------------------------------------------

template <int LA, int LB, int LO>
__device__ __forceinline__ void tp_accum(const float* __restrict__ R, float w,
                                         const float* xa, const float* xb, float* sph) {
  constexpr int NA = 2 * LA + 1, NB = 2 * LB + 1, NC = 2 * LO + 1;
#pragma unroll
  for (int a = 0; a < NA; ++a) {
#pragma unroll
    for (int b = 0; b < NB; ++b) {
      float xab = xa[a] * xb[b] * w;
#pragma unroll
      for (int c = 0; c < NC; ++c) sph[c] = fmaf(xab, R[(a * NB + b) * NC + c], sph[c]);
    }
  }
}

__global__ __launch_bounds__(256) void mega_node_kernel(
    const float* __restrict__ x_scalar, const float* __restrict__ x_sph,
    const int* __restrict__ batch, const float* __restrict__ W0, const float* __restrict__ W1,
    const float* __restrict__ W2, const float* __restrict__ A1, const float* __restrict__ b1,
    const float* __restrict__ A2, const float* __restrict__ b2, const float* __restrict__ p0,
    const float* __restrict__ p1, const float* __restrict__ p2, const float* __restrict__ cg_g,
    float* __restrict__ out, int N) {
  __shared__ float h_lds[8][64];
  __shared__ float cg[N_CG_FLOATS];
  __shared__ float xs_lds[8 * 128];
  __shared__ float sp_lds[8 * 480];

  const int t = threadIdx.x;
  const int b0 = blockIdx.x * 8;
  const int nb = min(8, N - b0);

  // ---- stage CG table + this block's input rows (coalesced float4)
  for (int i = t; i < N_CG_FLOATS; i += 256) cg[i] = cg_g[i];
  {
    const float4* src = (const float4*)(x_scalar + (long)b0 * 128);
    float4* dst = (float4*)xs_lds;
    const int nf4 = nb * 128 / 4;  // <= 256
    for (int i = t; i < nf4; i += 256) dst[i] = src[i];
    const float4* src2 = (const float4*)(x_sph + (long)b0 * 480);
    float4* dst2 = (float4*)sp_lds;
    const int nf42 = nb * 480 / 4;  // <= 960
    for (int i = t; i < nf42; i += 256) dst2[i] = src2[i];
  }
  __syncthreads();

  const int nl = t >> 5;  // node within block (0..7)
  const int v = t & 31;   // TP channel
  const bool active = (nl < nb);
  const int nl_c = active ? nl : (nb - 1);
  const int n = b0 + nl_c;

  // ---- h = silu(x_scalar @ A1 + b1); this lane computes cols v and v+32
  const float* xr = xs_lds + nl_c * 128;
  float a0 = b1[v], a1 = b1[v + 32];
  for (int j = 0; j < 128; ++j) {
    float xv = xr[j];
    a0 = fmaf(xv, A1[j * 64 + v], a0);
    a1 = fmaf(xv, A1[j * 64 + v + 32], a1);
  }
  h_lds[nl][v] = a0 / (1.0f + __expf(-a0));
  h_lds[nl][v + 32] = a1 / (1.0f + __expf(-a1));
  __syncthreads();

  // ---- channel mixes (out channel = v) + per-l RMS norm
  const float* sr = sp_lds + nl_c * 480;
  float y0 = 0.f;
  for (int u = 0; u < 128; ++u) y0 = fmaf(sr[u], W0[u * 32 + v], y0);
  y0 *= 0.08838834764831845f;  // 1/sqrt(128)

  float y1[3] = {0.f, 0.f, 0.f};
  for (int u = 0; u < 64; ++u) {
    float wv = W1[u * 32 + v];
    const float* xp = sr + 128 + u * 3;
    y1[0] = fmaf(xp[0], wv, y1[0]);
    y1[1] = fmaf(xp[1], wv, y1[1]);
    y1[2] = fmaf(xp[2], wv, y1[2]);
  }
  y1[0] *= 0.125f; y1[1] *= 0.125f; y1[2] *= 0.125f;  // 1/sqrt(64)

  float y2[5] = {0.f, 0.f, 0.f, 0.f, 0.f};
  for (int u = 0; u < 32; ++u) {
    float wv = W2[u * 32 + v];
    const float* xp = sr + 320 + u * 5;
#pragma unroll
    for (int m = 0; m < 5; ++m) y2[m] = fmaf(xp[m], wv, y2[m]);
  }
#pragma unroll
  for (int m = 0; m < 5; ++m) y2[m] *= 0.17677669529663687f;  // 1/sqrt(32)

  float s0 = y0 * y0;
  float s1 = y1[0] * y1[0] + y1[1] * y1[1] + y1[2] * y1[2];
  float s2 = 0.f;
#pragma unroll
  for (int m = 0; m < 5; ++m) s2 = fmaf(y2[m], y2[m], s2);
#pragma unroll
  for (int msk = 16; msk >= 1; msk >>= 1) {
    s0 += __shfl_xor(s0, msk);
    s1 += __shfl_xor(s1, msk);
    s2 += __shfl_xor(s2, msk);
  }
  const float inv0 = 1.0f / sqrtf(s0 * (1.0f / 32.0f) + 1e-5f);
  const float inv1 = 1.0f / sqrtf(s1 * (1.0f / 96.0f) + 1e-5f);
  const float inv2 = 1.0f / sqrtf(s2 * (1.0f / 160.0f) + 1e-5f);
  float xs0[1] = {y0 * inv0};
  float xs1[3] = {y1[0] * inv1, y1[1] * inv1, y1[2] * inv1};
  float xs2[5];
#pragma unroll
  for (int m = 0; m < 5; ++m) xs2[m] = y2[m] * inv2;

  // ---- TP weights: one pass over k computing all 9 columns
  float wv9[9];
#pragma unroll
  for (int i = 0; i < 9; ++i) wv9[i] = b2[i * 32 + v];
  {
    const float* hp = h_lds[nl];
    for (int k = 0; k < 64; ++k) {
      float hk = hp[k];
      const float* arow = A2 + k * 288 + v;
#pragma unroll
      for (int i = 0; i < 9; ++i) wv9[i] = fmaf(hk, arow[i * 32], wv9[i]);
    }
  }

  // ---- 9 TP instructions; coef folds alpha * p_path / sqrt(P)
  float sph0[1] = {0.f};
  float sph1[3] = {0.f, 0.f, 0.f};
  float sph2[5] = {0.f, 0.f, 0.f, 0.f, 0.f};
  const float invs32 = 0.17677669529663687f;             // 1/sqrt(32)
  const float k0 = invs32 / 3.0f;                        // sqrt(1)/(3*sqrt32)
  const float k1 = 1.7320508075688772f * invs32 / 2.0f;  // sqrt(3)/(2*sqrt32)
  const float k2 = 2.23606797749979f * invs32 / 4.0f;    // sqrt(5)/(4*sqrt32)

  tp_accum<0, 0, 0>(cg + 0,   wv9[0] * (k0 * p0[0]), xs0, xs0, sph0);
  tp_accum<1, 1, 0>(cg + 1,   wv9[1] * (k0 * p0[1]), xs1, xs1, sph0);
  tp_accum<2, 2, 0>(cg + 10,  wv9[2] * (k0 * p0[2]), xs2, xs2, sph0);
  tp_accum<1, 1, 1>(cg + 35,  wv9[3] * (k1 * p1[0]), xs1, xs1, sph1);
  tp_accum<2, 2, 1>(cg + 62,  wv9[4] * (k1 * p1[1]), xs2, xs2, sph1);
  tp_accum<0, 2, 2>(cg + 137, wv9[5] * (k2 * p2[0]), xs0, xs2, sph2);
  tp_accum<2, 0, 2>(cg + 162, wv9[6] * (k2 * p2[1]), xs2, xs0, sph2);
  tp_accum<1, 1, 2>(cg + 187, wv9[7] * (k2 * p2[2]), xs1, xs1, sph2);
  tp_accum<2, 2, 2>(cg + 232, wv9[8] * (k2 * p2[3]), xs2, xs2, sph2);

  // ---- reduce sph over the 32 channel lanes
#pragma unroll
  for (int msk = 16; msk >= 1; msk >>= 1) {
    sph0[0] += __shfl_xor(sph0[0], msk);
#pragma unroll
    for (int m = 0; m < 3; ++m) sph1[m] += __shfl_xor(sph1[m], msk);
#pragma unroll
    for (int m = 0; m < 5; ++m) sph2[m] += __shfl_xor(sph2[m], msk);
  }

  // ---- cartesian transform + rolled segment-sum
  if (v == 0 && active) {
    const float* qb0 = cg + 357;
    const float* qb1 = cg + 366;
    const float* qb2 = cg + 393;
    float* og = out + (long)batch[n] * 9;
#pragma unroll
    for (int i = 0; i < 3; ++i) {
#pragma unroll
      for (int j = 0; j < 3; ++j) {
        float val = sph0[0] * qb0[i * 3 + j];
#pragma unroll
        for (int m = 0; m < 3; ++m) val = fmaf(sph1[m], qb1[(i * 3 + j) * 3 + m], val);
#pragma unroll
        for (int m = 0; m < 5; ++m) val = fmaf(sph2[m], qb2[(i * 3 + j) * 5 + m], val);
        // out[b, (i+1)%3, (j+1)%3] = g[b, i, j]
        atomicAdd(&og[((i + 1) % 3) * 3 + ((j + 1) % 3)], val);
      }
    }
  }
}

// ---------------------------------------------------------------------------

extern "C" void kernel_launch(void* const* d_in, const int* in_sizes, int n_in,
                              void* d_out, int out_size, void* d_ws, size_t ws_size,
                              hipStream_t stream) {
  const float* x_scalar = (const float*)d_in[0];
  const float* x_sph    = (const float*)d_in[1];
  const int*   batch    = (const int*)d_in[2];
  const float* W0 = (const float*)d_in[4];
  const float* W1 = (const float*)d_in[5];
  const float* W2 = (const float*)d_in[6];
  const float* A1 = (const float*)d_in[7];
  const float* b1 = (const float*)d_in[8];
  const float* A2 = (const float*)d_in[9];
  const float* b2 = (const float*)d_in[10];
  const float* p0 = (const float*)d_in[11];
  const float* p1 = (const float*)d_in[12];
  const float* p2 = (const float*)d_in[13];
  float* out = (float*)d_out;
  float* ws  = (float*)d_ws;

  const int N = in_sizes[0] / 128;

  hipMemsetAsync(d_out, 0, (size_t)out_size * sizeof(float), stream);
  setup_cg_par<<<12, 128, 0, stream>>>(ws);
  const int blocks = (N + 7) / 8;
  mega_node_kernel<<<blocks, 256, 0, stream>>>(x_scalar, x_sph, batch, W0, W1, W2, A1, b1, A2,
                                               b2, p0, p1, p2, ws, out, N);
}